// Round 10
// baseline (324.495 us; speedup 1.0000x reference)
//
#include <hip/hip_runtime.h>
#include <hip/hip_cooperative_groups.h>
#include <math.h>

namespace cgx = cooperative_groups;

// Quantized softmax over axis 1 of x(8, 4096, 1024) fp32.
// Groups: (b, c) column, 8192 groups of 4096 elements (stride 1024 floats).
//
// Round-10: row-chunk-EVERYWHERE cooperative kernel (R7 structure, VGPR fixed).
// Evidence ledger: every column-slab phase ran at 0.5-1.9 TB/s (R5/R6/R8/R9-K3:
// waves touch 16-64B segments at 4KB stride). Row-chunk waves (1KB contiguous)
// are the only fast pattern. R7 was row-chunk but died of VGPR=28 starvation
// (launch_bounds min-waves=8). Here: 512 blocks x 512 thr, launch_bounds(512,4)
// -> 2 blocks/CU co-resident, VGPR cap 128, 8-deep load batches.
//   A: read x (NT, row-chunk) -> codes(ws) + per-(32row-chunk, g) max/min.
//   B: 16 groups/block reduce partials -> gmv[g] (code), dg[g].
//   C: redundant amax from dg[32KB]; e_q partial sums -> psum[128][8192].
//   D: 16 groups/block reduce psum -> sarr[g].
//   E: redundant max/min s from sarr[32KB]; derive scales; write out (NT).
// No atomics anywhere; 4 grid syncs; deterministic.
// Fallback: proven round-3 5-kernel path (101 us).

typedef float       f4 __attribute__((ext_vector_type(4)));
typedef signed char c4 __attribute__((ext_vector_type(4)));

static constexpr int Bdim = 8;
static constexpr int Jdim = 4096;
static constexpr int Cdim = 1024;
static constexpr int NG   = Bdim * Cdim;      // 8192 groups

static constexpr int FGRID = 512;             // (b, 64-row slab): 8 x 64
static constexpr int FBLK  = 512;             // 8 waves
static constexpr int NCH   = 128;             // 32-row chunks per group

// ws byte offsets
static constexpr size_t GMV_B   = 0;                      // f32[8192] gmax CODE
static constexpr size_t DG_B    = 32768;                  // f32[8192] range d
static constexpr size_t SARR_B  = 65536;                  // f32[8192] group sums
static constexpr size_t PMAX_B  = 131072;                 // i8[128][8192] 1MB
static constexpr size_t PMIN_B  = PMAX_B + (size_t)NCH * NG;
static constexpr size_t PSUM_B  = PMIN_B + (size_t)NCH * NG;   // f32[128][8192] 4MB
static constexpr size_t CODES_B = 8388608;                // i8 32MB
static constexpr size_t WS_NEED = CODES_B + 33554432;     // 40MB

__device__ __forceinline__ float code8f(float x, float sinv) {
    // int8 code as float; rintf = round-half-even matches jnp.round
    return fminf(fmaxf(rintf(x * sinv), -128.0f), 127.0f);
}
// e_q = fq16(exp(fq16(clip(xq - gmax, -12, 0)))); scale_e = 1/32767 exactly
// (group-max element has sub==0 -> e==1 -> absmax(e)==1).
__device__ __forceinline__ float eq_from(float xq, float gmv, float ssub_inv, float ssub) {
    float sub = fminf(fmaxf(xq - gmv, -12.0f), 0.0f);
    float q   = rintf(sub * ssub_inv);
    float e   = __expf(q * ssub);
    return rintf(e * 32767.0f) * (1.0f / 32767.0f);
}
__device__ __forceinline__ f4 fmax4v(f4 a, f4 b) {
    f4 r; r[0]=fmaxf(a[0],b[0]); r[1]=fmaxf(a[1],b[1]);
    r[2]=fmaxf(a[2],b[2]); r[3]=fmaxf(a[3],b[3]); return r;
}
__device__ __forceinline__ f4 fmin4v(f4 a, f4 b) {
    f4 r; r[0]=fminf(a[0],b[0]); r[1]=fminf(a[1],b[1]);
    r[2]=fminf(a[2],b[2]); r[3]=fminf(a[3],b[3]); return r;
}

__global__ __launch_bounds__(FBLK, 4) void k_fused(const float* __restrict__ x,
                                                   const float* __restrict__ scale,
                                                   float* __restrict__ out,
                                                   char* __restrict__ ws) {
    const int bid = blockIdx.x;
    const int b   = bid >> 6;            // batch 0..7
    const int jq  = bid & 63;            // 64-row slab
    const int t   = threadIdx.x;
    const int c0  = (t & 255) * 4;       // 4 columns
    const int rh  = t >> 8;              // 0/1: 32-row half
    const int w   = t >> 6;              // wave 0..7
    const int l   = t & 63;              // lane
    const float s    = scale[0];
    const float sinv = 1.0f / s;

    float*       gmv   = (float*)(ws + GMV_B);
    float*       dg    = (float*)(ws + DG_B);
    float*       sarr  = (float*)(ws + SARR_B);
    signed char* pmax8 = (signed char*)(ws + PMAX_B);
    signed char* pmin8 = (signed char*)(ws + PMIN_B);
    float*       psum  = (float*)(ws + PSUM_B);
    signed char* codes = (signed char*)(ws + CODES_B);

    const int    ch    = jq * 2 + rh;                       // 0..127
    const int    row0  = jq * 64 + rh * 32;
    const size_t base  = ((size_t)(b * Jdim + row0)) * Cdim + c0;
    const size_t pidx  = (size_t)ch * NG + b * Cdim + c0;   // [ch][g] coalesced

    __shared__ int   smx[32][16], smn[32][16];
    __shared__ float sps[32][16];
    __shared__ float sredA[8], sredB[8];
    __shared__ float bc[3];

    // ---------- Phase A: read x (NT, 8-deep), quantize -> codes + partials
    {
        f4 vmax = {-1e30f, -1e30f, -1e30f, -1e30f};
        f4 vmin = { 1e30f,  1e30f,  1e30f,  1e30f};
#pragma unroll
        for (int r0 = 0; r0 < 32; r0 += 8) {
            f4 v[8];
#pragma unroll
            for (int j = 0; j < 8; ++j)              // 8 loads in flight
                v[j] = __builtin_nontemporal_load(
                    reinterpret_cast<const f4*>(x + base + (size_t)(r0 + j) * Cdim));
#pragma unroll
            for (int j = 0; j < 8; ++j) {
                f4 q;
                q[0] = code8f(v[j][0], sinv); q[1] = code8f(v[j][1], sinv);
                q[2] = code8f(v[j][2], sinv); q[3] = code8f(v[j][3], sinv);
                vmax = fmax4v(vmax, q); vmin = fmin4v(vmin, q);
                *reinterpret_cast<c4*>(codes + base + (size_t)(r0 + j) * Cdim) =
                    (c4){(signed char)(int)q[0], (signed char)(int)q[1],
                         (signed char)(int)q[2], (signed char)(int)q[3]};
            }
        }
        *reinterpret_cast<c4*>(pmax8 + pidx) =
            (c4){(signed char)(int)vmax[0], (signed char)(int)vmax[1],
                 (signed char)(int)vmax[2], (signed char)(int)vmax[3]};
        *reinterpret_cast<c4*>(pmin8 + pidx) =
            (c4){(signed char)(int)vmin[0], (signed char)(int)vmin[1],
                 (signed char)(int)vmin[2], (signed char)(int)vmin[3]};
    }
    cgx::this_grid().sync();

    // ---------- Phase B: 16 groups/block -> gmv[g] (code), dg[g]
    {
        const int gi  = t & 15;                  // group within block
        const int sub = t >> 4;                  // 0..31 reducers
        const int g   = bid * 16 + gi;
        int mx = -128, mn = 127;
#pragma unroll
        for (int k = 0; k < 4; ++k) {
            const size_t idx = (size_t)(sub * 4 + k) * NG + g;
            mx = max(mx, (int)pmax8[idx]);
            mn = min(mn, (int)pmin8[idx]);
        }
        smx[sub][gi] = mx; smn[sub][gi] = mn;
        __syncthreads();
        for (int off = 16; off; off >>= 1) {
            if (sub < off) {
                smx[sub][gi] = max(smx[sub][gi], smx[sub + off][gi]);
                smn[sub][gi] = min(smn[sub][gi], smn[sub + off][gi]);
            }
            __syncthreads();
        }
        if (t < 16) {
            const int g2 = bid * 16 + t;
            const float gmaxv = (float)smx[0][t];
            gmv[g2] = gmaxv;                     // CODE; consumers multiply by s
            dg[g2]  = fminf(12.0f, gmaxv * s - (float)smn[0][t] * s);  // exact fp
        }
    }
    cgx::this_grid().sync();

    // ---------- Phase C: redundant amax; e_q partial sums
    {
        float m = 0.0f;
        const f4* dgp = reinterpret_cast<const f4*>(dg);
#pragma unroll
        for (int i = 0; i < 4; ++i) {            // thread reads dg[t*16 .. +16)
            const f4 dv = dgp[t * 4 + i];
            m = fmaxf(m, fmaxf(fmaxf(dv[0], dv[1]), fmaxf(dv[2], dv[3])));
        }
#pragma unroll
        for (int off = 1; off < 64; off <<= 1) m = fmaxf(m, __shfl_xor(m, off));
        if (l == 0) sredA[w] = m;
        __syncthreads();
        if (t == 0) {
            float mm = sredA[0];
#pragma unroll
            for (int i = 1; i < 8; ++i) mm = fmaxf(mm, sredA[i]);
            bc[0] = mm;
        }
        __syncthreads();
    }
    const float amax = fmaxf(bc[0], 1e-9f);
    const float ssub = amax / 32767.0f;
    const float ssub_inv = 1.0f / ssub;
    const f4 gmc = *reinterpret_cast<const f4*>(gmv + b * Cdim + c0);
    const f4 gm  = {gmc[0] * s, gmc[1] * s, gmc[2] * s, gmc[3] * s};
    {
        f4 acc = {0.f, 0.f, 0.f, 0.f};
#pragma unroll 8
        for (int r = 0; r < 32; ++r) {           // codes L2-hot (same block wrote)
            const c4 q = *reinterpret_cast<const c4*>(codes + base + (size_t)r * Cdim);
            acc[0] += eq_from((float)q[0] * s, gm[0], ssub_inv, ssub);
            acc[1] += eq_from((float)q[1] * s, gm[1], ssub_inv, ssub);
            acc[2] += eq_from((float)q[2] * s, gm[2], ssub_inv, ssub);
            acc[3] += eq_from((float)q[3] * s, gm[3], ssub_inv, ssub);
        }
        *reinterpret_cast<f4*>(psum + pidx) = acc;   // [ch][g] coalesced
    }
    cgx::this_grid().sync();

    // ---------- Phase D: 16 groups/block -> sarr[g]
    {
        const int gi  = t & 15;
        const int sub = t >> 4;
        const int g   = bid * 16 + gi;
        float sum = 0.0f;
#pragma unroll
        for (int k = 0; k < 4; ++k)
            sum += psum[(size_t)(sub * 4 + k) * NG + g];
        sps[sub][gi] = sum;
        __syncthreads();
        for (int off = 16; off; off >>= 1) {
            if (sub < off) sps[sub][gi] += sps[sub + off][gi];
            __syncthreads();
        }
        if (t < 16) sarr[bid * 16 + t] = sps[0][t];
    }
    cgx::this_grid().sync();

    // ---------- Phase E: redundant max/min s; derive scales; write out
    {
        float mx = -1e30f, mn = 1e30f;
        const f4* sp = reinterpret_cast<const f4*>(sarr);
#pragma unroll
        for (int i = 0; i < 4; ++i) {
            const f4 sv = sp[t * 4 + i];
            mx = fmaxf(mx, fmaxf(fmaxf(sv[0], sv[1]), fmaxf(sv[2], sv[3])));
            mn = fminf(mn, fminf(fminf(sv[0], sv[1]), fminf(sv[2], sv[3])));
        }
#pragma unroll
        for (int off = 1; off < 64; off <<= 1) {
            mx = fmaxf(mx, __shfl_xor(mx, off));
            mn = fminf(mn, __shfl_xor(mn, off));
        }
        if (l == 0) { sredA[w] = mx; sredB[w] = mn; }
        __syncthreads();
        if (t == 0) {
            float gmx = sredA[0], gmn = sredB[0];
#pragma unroll
            for (int i = 1; i < 8; ++i) {
                gmx = fmaxf(gmx, sredA[i]); gmn = fminf(gmn, sredB[i]);
            }
            bc[1] = gmx; bc[2] = gmn;
        }
        __syncthreads();
    }
    const float max_s = bc[1], min_s = bc[2];
    // fq monotone: min s_q = fq(min s); max r = 1/min s_q; max r_q = fq(max r)
    const float scale_s = fmaxf(max_s, 1e-9f) / 32767.0f;
    const float ss_inv  = 1.0f / scale_s;
    const float minsq   = fminf(fmaxf(rintf(min_s * ss_inv), -32768.0f), 32767.0f) * scale_s;
    const float maxr    = 1.0f / minsq;
    const float scale_r = fmaxf(maxr, 1e-9f) / 32767.0f;
    const float sr_inv  = 1.0f / scale_r;
    const float maxrq   = fminf(fmaxf(rintf(maxr * sr_inv), -32768.0f), 32767.0f) * scale_r;
    const float scale_out = fmaxf(maxrq, 1e-9f) / 127.0f;
    const float so_inv  = 1.0f / scale_out;

    const f4 s4 = *reinterpret_cast<const f4*>(sarr + b * Cdim + c0);
    f4 rq;
#pragma unroll
    for (int i = 0; i < 4; ++i) {
        float qv = fminf(fmaxf(rintf(s4[i] * ss_inv), -32768.0f), 32767.0f) * scale_s;
        rq[i] = fminf(fmaxf(rintf((1.0f / qv) * sr_inv), -32768.0f), 32767.0f) * scale_r;
    }
#pragma unroll
    for (int r0 = 0; r0 < 32; r0 += 8) {
        c4 qv[8];
#pragma unroll
        for (int j = 0; j < 8; ++j)
            qv[j] = *reinterpret_cast<const c4*>(codes + base + (size_t)(r0 + j) * Cdim);
#pragma unroll
        for (int j = 0; j < 8; ++j) {
            const float e0 = eq_from((float)qv[j][0] * s, gm[0], ssub_inv, ssub) * rq[0];
            const float e1 = eq_from((float)qv[j][1] * s, gm[1], ssub_inv, ssub) * rq[1];
            const float e2 = eq_from((float)qv[j][2] * s, gm[2], ssub_inv, ssub) * rq[2];
            const float e3 = eq_from((float)qv[j][3] * s, gm[3], ssub_inv, ssub) * rq[3];
            f4 o;
            o[0] = fminf(fmaxf(rintf(e0 * so_inv), -128.0f), 127.0f) * scale_out;
            o[1] = fminf(fmaxf(rintf(e1 * so_inv), -128.0f), 127.0f) * scale_out;
            o[2] = fminf(fmaxf(rintf(e2 * so_inv), -128.0f), 127.0f) * scale_out;
            o[3] = fminf(fmaxf(rintf(e3 * so_inv), -128.0f), 127.0f) * scale_out;
            __builtin_nontemporal_store(o,
                reinterpret_cast<f4*>(out + base + (size_t)(r0 + j) * Cdim));
        }
    }
}

// ======================= round-3 fallback path (proven, 101 us) =======================
static constexpr int JCHUNK = 16;
static constexpr int NJC = Jdim / JCHUNK;
static constexpr int PSIZE = Bdim * NJC * Cdim;

static constexpr int SC_OFF   = 0;
static constexpr int GMAX_OFF = 16;
static constexpr int S_OFF    = GMAX_OFF + NG;
static constexpr int PS_OFF   = S_OFF + NG;
static constexpr size_t FB_BYTES    = ((size_t)PS_OFF + PSIZE) * 4;
static constexpr size_t CODES_BYTES = (size_t)Bdim * Jdim * Cdim;
static constexpr size_t P_BYTES     = 2 * (size_t)PSIZE;

__device__ __forceinline__ f4 shfl_xor4(f4 v, int off) {
    f4 r; r[0] = __shfl_xor(v[0], off); r[1] = __shfl_xor(v[1], off);
    r[2] = __shfl_xor(v[2], off); r[3] = __shfl_xor(v[3], off); return r;
}

template <bool WC>
__global__ __launch_bounds__(256) void k_pass1(const float* __restrict__ x,
                                               const float* __restrict__ scale,
                                               float* __restrict__ fbuf,
                                               signed char* __restrict__ codes,
                                               signed char* __restrict__ pmax,
                                               signed char* __restrict__ pmin) {
    if (blockIdx.x == 0 && threadIdx.x == 0) {
        fbuf[SC_OFF + 0] = 0.0f;
        fbuf[SC_OFF + 1] = 0.0f;
        fbuf[SC_OFF + 2] = __int_as_float(0x7f800000);
    }
    const int b  = blockIdx.x / NJC;
    const int jc = blockIdx.x % NJC;
    const int c0 = threadIdx.x * 4;
    const float sinv = 1.0f / scale[0];
    const size_t base = ((size_t)(b * Jdim + jc * JCHUNK)) * Cdim + c0;

    f4 vmax = {-1e30f, -1e30f, -1e30f, -1e30f};
    f4 vmin = { 1e30f,  1e30f,  1e30f,  1e30f};
    #pragma unroll 4
    for (int r = 0; r < JCHUNK; ++r) {
        const f4 v = __builtin_nontemporal_load(
            reinterpret_cast<const f4*>(x + base + (size_t)r * Cdim));
        f4 q;
        q[0] = code8f(v[0], sinv); q[1] = code8f(v[1], sinv);
        q[2] = code8f(v[2], sinv); q[3] = code8f(v[3], sinv);
        vmax = fmax4v(vmax, q); vmin = fmin4v(vmin, q);
        if (WC) {
            c4 pk = {(signed char)(int)q[0], (signed char)(int)q[1],
                     (signed char)(int)q[2], (signed char)(int)q[3]};
            *reinterpret_cast<c4*>(codes + base + (size_t)r * Cdim) = pk;
        }
    }
    const size_t pidx = ((size_t)(b * NJC + jc)) * Cdim + c0;
    c4 mx = {(signed char)(int)vmax[0], (signed char)(int)vmax[1],
             (signed char)(int)vmax[2], (signed char)(int)vmax[3]};
    c4 mn = {(signed char)(int)vmin[0], (signed char)(int)vmin[1],
             (signed char)(int)vmin[2], (signed char)(int)vmin[3]};
    *reinterpret_cast<c4*>(pmax + pidx) = mx;
    *reinterpret_cast<c4*>(pmin + pidx) = mn;
}

__global__ __launch_bounds__(256) void k_reduce1(const float* __restrict__ scale,
                                                 float* __restrict__ fbuf,
                                                 const signed char* __restrict__ pmax,
                                                 const signed char* __restrict__ pmin) {
    const int b   = blockIdx.x / 32;
    const int ct  = blockIdx.x % 32;
    const int ci  = threadIdx.x & 31;
    const int sub = threadIdx.x >> 5;
    const int c   = ct * 32 + ci;

    int mx = -128, mn = 127;
    for (int jc = sub; jc < NJC; jc += 8) {
        const size_t idx = ((size_t)(b * NJC + jc)) * Cdim + c;
        mx = max(mx, (int)pmax[idx]);
        mn = min(mn, (int)pmin[idx]);
    }
    __shared__ int smx[8][32], smn[8][32];
    smx[sub][ci] = mx; smn[sub][ci] = mn;
    __syncthreads();
    for (int off = 4; off; off >>= 1) {
        if (sub < off) {
            smx[sub][ci] = max(smx[sub][ci], smx[sub + off][ci]);
            smn[sub][ci] = min(smn[sub][ci], smn[sub + off][ci]);
        }
        __syncthreads();
    }
    __shared__ float sd[32];
    if (sub == 0) {
        const float s = scale[0];
        fbuf[GMAX_OFF + b * Cdim + c] = (float)smx[0][ci];
        sd[ci] = fminf(12.0f, (float)smx[0][ci] * s - (float)smn[0][ci] * s);
    }
    __syncthreads();
    if (threadIdx.x == 0) {
        float m = sd[0];
        #pragma unroll
        for (int i = 1; i < 32; ++i) m = fmaxf(m, sd[i]);
        atomicMax(reinterpret_cast<unsigned int*>(fbuf + SC_OFF + 0), __float_as_uint(m));
    }
}

template <bool UC>
__global__ __launch_bounds__(256) void k_pass2(const float* __restrict__ x,
                                               const signed char* __restrict__ codes,
                                               const float* __restrict__ scale,
                                               float* __restrict__ fbuf) {
    const int b  = blockIdx.x / NJC;
    const int jc = blockIdx.x % NJC;
    const int c0 = threadIdx.x * 4;
    const float s = scale[0];
    const float sinv = 1.0f / s;
    const float amax = fmaxf(fbuf[SC_OFF + 0], 1e-9f);
    const float ssub = amax / 32767.0f;
    const float ssub_inv = 1.0f / ssub;
    const f4 gmc = *reinterpret_cast<const f4*>(fbuf + GMAX_OFF + b * Cdim + c0);
    const float gm0 = gmc[0]*s, gm1 = gmc[1]*s, gm2 = gmc[2]*s, gm3 = gmc[3]*s;
    const size_t base = ((size_t)(b * Jdim + jc * JCHUNK)) * Cdim + c0;

    float a0 = 0.f, a1 = 0.f, a2 = 0.f, a3 = 0.f;
    #pragma unroll 4
    for (int r = 0; r < JCHUNK; ++r) {
        float xq0, xq1, xq2, xq3;
        if (UC) {
            const c4 q = *reinterpret_cast<const c4*>(codes + base + (size_t)r * Cdim);
            xq0 = (float)q[0]*s; xq1 = (float)q[1]*s; xq2 = (float)q[2]*s; xq3 = (float)q[3]*s;
        } else {
            const f4 v = *reinterpret_cast<const f4*>(x + base + (size_t)r * Cdim);
            xq0 = code8f(v[0], sinv)*s; xq1 = code8f(v[1], sinv)*s;
            xq2 = code8f(v[2], sinv)*s; xq3 = code8f(v[3], sinv)*s;
        }
        a0 += eq_from(xq0, gm0, ssub_inv, ssub);
        a1 += eq_from(xq1, gm1, ssub_inv, ssub);
        a2 += eq_from(xq2, gm2, ssub_inv, ssub);
        a3 += eq_from(xq3, gm3, ssub_inv, ssub);
    }
    f4 acc = {a0, a1, a2, a3};
    *reinterpret_cast<f4*>(fbuf + PS_OFF + ((size_t)(b * NJC + jc)) * Cdim + c0) = acc;
}

__global__ __launch_bounds__(256) void k_reduce2(float* __restrict__ fbuf) {
    const int b   = blockIdx.x / 32;
    const int ct  = blockIdx.x % 32;
    const int ci  = threadIdx.x & 31;
    const int sub = threadIdx.x >> 5;
    const int c   = ct * 32 + ci;

    float p = 0.0f;
    for (int jc = sub; jc < NJC; jc += 8)
        p += fbuf[PS_OFF + ((size_t)(b * NJC + jc)) * Cdim + c];
    __shared__ float sp[8][32];
    sp[sub][ci] = p;
    __syncthreads();
    for (int off = 4; off; off >>= 1) {
        if (sub < off) sp[sub][ci] += sp[sub + off][ci];
        __syncthreads();
    }
    __shared__ float smx[32], smn[32];
    if (sub == 0) {
        const float tv = sp[0][ci];
        fbuf[S_OFF + b * Cdim + c] = tv;
        smx[ci] = tv; smn[ci] = tv;
    }
    __syncthreads();
    if (threadIdx.x == 0) {
        float mx = smx[0], mn = smn[0];
        #pragma unroll
        for (int i = 1; i < 32; ++i) { mx = fmaxf(mx, smx[i]); mn = fminf(mn, smn[i]); }
        atomicMax(reinterpret_cast<unsigned int*>(fbuf + SC_OFF + 1), __float_as_uint(mx));
        atomicMin(reinterpret_cast<unsigned int*>(fbuf + SC_OFF + 2), __float_as_uint(mn));
    }
}

template <bool UC>
__global__ __launch_bounds__(256) void k_pass3(const float* __restrict__ x,
                                               const signed char* __restrict__ codes,
                                               const float* __restrict__ scale,
                                               const float* __restrict__ fbuf,
                                               float* __restrict__ out) {
    const int b  = blockIdx.x / NJC;
    const int jc = blockIdx.x % NJC;
    const int c0 = threadIdx.x * 4;
    const float s = scale[0];
    const float sinv = 1.0f / s;

    const float amax = fmaxf(fbuf[SC_OFF + 0], 1e-9f);
    const float ssub = amax / 32767.0f;
    const float ssub_inv = 1.0f / ssub;

    const float max_s = fbuf[SC_OFF + 1];
    const float min_s = fbuf[SC_OFF + 2];
    const float scale_s = fmaxf(max_s, 1e-9f) / 32767.0f;
    const float ss_inv = 1.0f / scale_s;
    const float minsq = fminf(fmaxf(rintf(min_s * ss_inv), -32768.0f), 32767.0f) * scale_s;
    const float maxr  = 1.0f / minsq;
    const float scale_r = fmaxf(maxr, 1e-9f) / 32767.0f;
    const float sr_inv  = 1.0f / scale_r;
    const float maxrq = fminf(fmaxf(rintf(maxr * sr_inv), -32768.0f), 32767.0f) * scale_r;
    const float scale_out = fmaxf(maxrq, 1e-9f) / 127.0f;
    const float so_inv = 1.0f / scale_out;

    const f4 gmc = *reinterpret_cast<const f4*>(fbuf + GMAX_OFF + b * Cdim + c0);
    const float gm0 = gmc[0]*s, gm1 = gmc[1]*s, gm2 = gmc[2]*s, gm3 = gmc[3]*s;
    const f4 s4 = *reinterpret_cast<const f4*>(fbuf + S_OFF + b * Cdim + c0);

    f4 rq;
    {
        float q0 = fminf(fmaxf(rintf(s4[0] * ss_inv), -32768.0f), 32767.0f) * scale_s;
        float q1 = fminf(fmaxf(rintf(s4[1] * ss_inv), -32768.0f), 32767.0f) * scale_s;
        float q2 = fminf(fmaxf(rintf(s4[2] * ss_inv), -32768.0f), 32767.0f) * scale_s;
        float q3 = fminf(fmaxf(rintf(s4[3] * ss_inv), -32768.0f), 32767.0f) * scale_s;
        rq[0] = fminf(fmaxf(rintf((1.0f/q0) * sr_inv), -32768.0f), 32767.0f) * scale_r;
        rq[1] = fminf(fmaxf(rintf((1.0f/q1) * sr_inv), -32768.0f), 32767.0f) * scale_r;
        rq[2] = fminf(fmaxf(rintf((1.0f/q2) * sr_inv), -32768.0f), 32767.0f) * scale_r;
        rq[3] = fminf(fmaxf(rintf((1.0f/q3) * sr_inv), -32768.0f), 32767.0f) * scale_r;
    }

    const size_t base = ((size_t)(b * Jdim + jc * JCHUNK)) * Cdim + c0;
    #pragma unroll 4
    for (int r = 0; r < JCHUNK; ++r) {
        float xq0, xq1, xq2, xq3;
        if (UC) {
            const c4 q = *reinterpret_cast<const c4*>(codes + base + (size_t)r * Cdim);
            xq0 = (float)q[0]*s; xq1 = (float)q[1]*s; xq2 = (float)q[2]*s; xq3 = (float)q[3]*s;
        } else {
            const f4 v = *reinterpret_cast<const f4*>(x + base + (size_t)r * Cdim);
            xq0 = code8f(v[0], sinv)*s; xq1 = code8f(v[1], sinv)*s;
            xq2 = code8f(v[2], sinv)*s; xq3 = code8f(v[3], sinv)*s;
        }
        float e0 = eq_from(xq0, gm0, ssub_inv, ssub) * rq[0];
        float e1 = eq_from(xq1, gm1, ssub_inv, ssub) * rq[1];
        float e2 = eq_from(xq2, gm2, ssub_inv, ssub) * rq[2];
        float e3 = eq_from(xq3, gm3, ssub_inv, ssub) * rq[3];
        f4 o;
        o[0] = fminf(fmaxf(rintf(e0 * so_inv), -128.0f), 127.0f) * scale_out;
        o[1] = fminf(fmaxf(rintf(e1 * so_inv), -128.0f), 127.0f) * scale_out;
        o[2] = fminf(fmaxf(rintf(e2 * so_inv), -128.0f), 127.0f) * scale_out;
        o[3] = fminf(fmaxf(rintf(e3 * so_inv), -128.0f), 127.0f) * scale_out;
        __builtin_nontemporal_store(o, reinterpret_cast<f4*>(out + base + (size_t)r * Cdim));
    }
}

extern "C" void kernel_launch(void* const* d_in, const int* in_sizes, int n_in,
                              void* d_out, int out_size, void* d_ws, size_t ws_size,
                              hipStream_t stream) {
    const float* x     = (const float*)d_in[0];
    const float* scale = (const float*)d_in[1];
    float* out = (float*)d_out;

    // ---- preferred: row-chunk cooperative kernel ----
    if (ws_size >= WS_NEED) {
        char* wsb = (char*)d_ws;
        const float* xa = x; const float* sa = scale; float* oa = out; char* wa = wsb;
        void* args[4] = {(void*)&xa, (void*)&sa, (void*)&oa, (void*)&wa};
        hipError_t err = hipLaunchCooperativeKernel((const void*)k_fused,
                                                    dim3(FGRID), dim3(FBLK),
                                                    args, 0, stream);
        if (err == hipSuccess) return;
    }

    // ---- fallback: proven round-3 5-kernel path ----
    const bool uc = ws_size >= CODES_BYTES + FB_BYTES + P_BYTES;
    signed char* codes = uc ? (signed char*)d_ws : nullptr;
    float* fbuf = uc ? (float*)((char*)d_ws + CODES_BYTES) : (float*)d_ws;
    signed char* pmax = (signed char*)((char*)fbuf + FB_BYTES);
    signed char* pmin = pmax + PSIZE;

    if (uc) {
        k_pass1<true ><<<Bdim * NJC, 256, 0, stream>>>(x, scale, fbuf, codes, pmax, pmin);
        k_reduce1<<<256, 256, 0, stream>>>(scale, fbuf, pmax, pmin);
        k_pass2<true ><<<Bdim * NJC, 256, 0, stream>>>(x, codes, scale, fbuf);
        k_reduce2<<<256, 256, 0, stream>>>(fbuf);
        k_pass3<true ><<<Bdim * NJC, 256, 0, stream>>>(x, codes, scale, fbuf, out);
    } else {
        k_pass1<false><<<Bdim * NJC, 256, 0, stream>>>(x, scale, fbuf, codes, pmax, pmin);
        k_reduce1<<<256, 256, 0, stream>>>(scale, fbuf, pmax, pmin);
        k_pass2<false><<<Bdim * NJC, 256, 0, stream>>>(x, codes, scale, fbuf);
        k_reduce2<<<256, 256, 0, stream>>>(fbuf);
        k_pass3<false><<<Bdim * NJC, 256, 0, stream>>>(x, codes, scale, fbuf, out);
    }
}

// Round 11
// 98.473 us; speedup vs baseline: 3.2953x; 3.2953x over previous
//
#include <hip/hip_runtime.h>
#include <math.h>

// Quantized softmax over axis 1 of x(8, 4096, 1024) fp32.
// Groups: (b, c) column, 8192 groups of 4096 elements (stride 1024 floats).
//
// Round-11: best-of-proven 5-kernel row-chunk pipeline. Cooperative fusion is
// dead (R10: fully-coalesced coop kernel = 312us; grid syncs ~50us EACH on
// MI355X). Column-slab phases are dead (R9: +11us even on L3-resident data).
//   K1 p1: read x (NT, 8-deep batches) -> codes(32MB) + [jc][g] max/min partials.
//   K2 r1: partials -> per-group gmax code + global amax_sub (atomicMax).
//   K3 p2: row-chunk, 8-deep code loads -> psum[jc][g] (16-row partial sums).
//   K4 r2: psum -> group sums sarr[g] + global max/min s (atomics).
//   K5 p3: codes + scalars -> out (NT stores, 8-deep).
// Atomics are uint max/min only (order-independent -> deterministic).
// Summation order matches R3 exactly -> absmax 8.544922e-4 reproducible.

typedef float       f4 __attribute__((ext_vector_type(4)));
typedef signed char c4 __attribute__((ext_vector_type(4)));

static constexpr int Bdim = 8;
static constexpr int Jdim = 4096;
static constexpr int Cdim = 1024;
static constexpr int NG   = Bdim * Cdim;       // 8192 groups

static constexpr int JC    = 16;               // rows per chunk
static constexpr int NJC   = Jdim / JC;        // 256 chunks per batch
static constexpr int GRID1 = Bdim * NJC;       // 2048 blocks for P1/P2/P3

// ---- ws byte offsets ----
static constexpr size_t SC_B    = 0;                               // f32[3]
static constexpr size_t GMV_B   = 4096;                            // f32[8192] gmax CODE
static constexpr size_t SARR_B  = GMV_B + (size_t)NG * 4;          // f32[8192] group sums
static constexpr size_t PMAX_B  = 131072;                          // i8[256][8192] = 2MB
static constexpr size_t PMIN_B  = PMAX_B + (size_t)NJC * NG;       // 2MB
static constexpr size_t PSUM_B  = PMIN_B + (size_t)NJC * NG;       // f32[256][8192] = 8MB
static constexpr size_t CODES_B = PSUM_B + (size_t)NJC * NG * 4;   // i8 32MB
static constexpr size_t WS_NEED = CODES_B + (size_t)Bdim * Jdim * Cdim;  // ~44MB

__device__ __forceinline__ float code8f(float x, float sinv) {
    // int8 code as float; rintf = round-half-even matches jnp.round
    return fminf(fmaxf(rintf(x * sinv), -128.0f), 127.0f);
}
// e_q = fq16(exp(fq16(clip(xq - gmax, -12, 0)))); scale_e = 1/32767 exactly
// (group-max element has sub==0 -> e==1 -> absmax(e)==1).
__device__ __forceinline__ float eq_from(float xq, float gmv, float ssub_inv, float ssub) {
    float sub = fminf(fmaxf(xq - gmv, -12.0f), 0.0f);
    float q   = rintf(sub * ssub_inv);
    float e   = __expf(q * ssub);
    return rintf(e * 32767.0f) * (1.0f / 32767.0f);
}
__device__ __forceinline__ f4 fmax4v(f4 a, f4 b) {
    f4 r; r[0]=fmaxf(a[0],b[0]); r[1]=fmaxf(a[1],b[1]);
    r[2]=fmaxf(a[2],b[2]); r[3]=fmaxf(a[3],b[3]); return r;
}
__device__ __forceinline__ f4 fmin4v(f4 a, f4 b) {
    f4 r; r[0]=fminf(a[0],b[0]); r[1]=fminf(a[1],b[1]);
    r[2]=fminf(a[2],b[2]); r[3]=fminf(a[3],b[3]); return r;
}

// ---------------- K1: quantize pass (validated R9 k_p1) ----------------
template <bool WC>
__global__ __launch_bounds__(256) void k_p1(const float* __restrict__ x,
                                            const float* __restrict__ scale,
                                            char* __restrict__ ws) {
    float* sc = (float*)(ws + SC_B);
    if (blockIdx.x == 0 && threadIdx.x == 0) {
        sc[0] = 0.0f;                        // amax_sub (atomicMax, >=0)
        sc[1] = 0.0f;                        // max_s    (atomicMax, >0)
        sc[2] = __int_as_float(0x7f800000);  // min_s = +inf (atomicMin)
    }
    const int b  = blockIdx.x / NJC;
    const int jc = blockIdx.x % NJC;
    const int c0 = threadIdx.x * 4;
    const float sinv = 1.0f / scale[0];
    const size_t base = ((size_t)(b * Jdim + jc * JC)) * Cdim + c0;
    signed char* codes = (signed char*)(ws + CODES_B);

    f4 vmax = {-1e30f, -1e30f, -1e30f, -1e30f};
    f4 vmin = { 1e30f,  1e30f,  1e30f,  1e30f};
#pragma unroll
    for (int r0 = 0; r0 < JC; r0 += 8) {
        f4 v[8];
#pragma unroll
        for (int j = 0; j < 8; ++j)                 // 8 loads in flight
            v[j] = __builtin_nontemporal_load(
                reinterpret_cast<const f4*>(x + base + (size_t)(r0 + j) * Cdim));
#pragma unroll
        for (int j = 0; j < 8; ++j) {
            f4 q;
            q[0] = code8f(v[j][0], sinv); q[1] = code8f(v[j][1], sinv);
            q[2] = code8f(v[j][2], sinv); q[3] = code8f(v[j][3], sinv);
            vmax = fmax4v(vmax, q); vmin = fmin4v(vmin, q);
            if (WC)
                *reinterpret_cast<c4*>(codes + base + (size_t)(r0 + j) * Cdim) =
                    (c4){(signed char)(int)q[0], (signed char)(int)q[1],
                         (signed char)(int)q[2], (signed char)(int)q[3]};
        }
    }
    const size_t pidx = (size_t)jc * NG + b * Cdim + c0;   // [jc][g] coalesced
    *reinterpret_cast<c4*>(ws + PMAX_B + pidx) =
        (c4){(signed char)(int)vmax[0], (signed char)(int)vmax[1],
             (signed char)(int)vmax[2], (signed char)(int)vmax[3]};
    *reinterpret_cast<c4*>(ws + PMIN_B + pidx) =
        (c4){(signed char)(int)vmin[0], (signed char)(int)vmin[1],
             (signed char)(int)vmin[2], (signed char)(int)vmin[3]};
}

// ---------------- K2: group gmax + global amax_sub (validated R9 k_r1) ----------------
__global__ __launch_bounds__(256) void k_r1(const float* __restrict__ scale,
                                            char* __restrict__ ws) {
    const signed char* pmax8 = (const signed char*)(ws + PMAX_B);
    const signed char* pmin8 = (const signed char*)(ws + PMIN_B);
    float* gmv = (float*)(ws + GMV_B);
    float* sc  = (float*)(ws + SC_B);

    const int ci  = threadIdx.x & 31;
    const int sub = threadIdx.x >> 5;           // 0..7
    const int g   = blockIdx.x * 32 + ci;       // 256 blocks x 32 groups

    int mx = -128, mn = 127;
    for (int jc = sub; jc < NJC; jc += 8) {
        const size_t idx = (size_t)jc * NG + g;
        mx = max(mx, (int)pmax8[idx]);
        mn = min(mn, (int)pmin8[idx]);
    }
    __shared__ int smx[8][32], smn[8][32];
    smx[sub][ci] = mx; smn[sub][ci] = mn;
    __syncthreads();
    for (int off = 4; off; off >>= 1) {
        if (sub < off) {
            smx[sub][ci] = max(smx[sub][ci], smx[sub + off][ci]);
            smn[sub][ci] = min(smn[sub][ci], smn[sub + off][ci]);
        }
        __syncthreads();
    }
    __shared__ float sd[32];
    if (sub == 0) {
        const float s = scale[0];
        gmv[g] = (float)smx[0][ci];             // stored as CODE
        sd[ci] = fminf(12.0f, (float)smx[0][ci] * s - (float)smn[0][ci] * s);
    }
    __syncthreads();
    if (threadIdx.x == 0) {
        float m = sd[0];
#pragma unroll
        for (int i = 1; i < 32; ++i) m = fmaxf(m, sd[i]);
        atomicMax(reinterpret_cast<unsigned int*>(sc + 0), __float_as_uint(m));
    }
}

// ---------------- K3: partial e_q sums (R3 P2 + 8-deep batching) ----------------
template <bool UC>
__global__ __launch_bounds__(256) void k_p2(const float* __restrict__ x,
                                            const float* __restrict__ scale,
                                            char* __restrict__ ws) {
    const int b  = blockIdx.x / NJC;
    const int jc = blockIdx.x % NJC;
    const int c0 = threadIdx.x * 4;
    const float s = scale[0];
    const float sinv = 1.0f / s;
    const float* sc  = (const float*)(ws + SC_B);
    const float* gmv = (const float*)(ws + GMV_B);
    float* psum = (float*)(ws + PSUM_B);
    const signed char* codes = (const signed char*)(ws + CODES_B);

    const float amax = fmaxf(sc[0], 1e-9f);
    const float ssub = amax / 32767.0f;
    const float ssub_inv = 1.0f / ssub;
    const f4 gmc = *reinterpret_cast<const f4*>(gmv + b * Cdim + c0);
    const f4 gm  = {gmc[0] * s, gmc[1] * s, gmc[2] * s, gmc[3] * s};
    const size_t base = ((size_t)(b * Jdim + jc * JC)) * Cdim + c0;

    f4 acc = {0.f, 0.f, 0.f, 0.f};
#pragma unroll
    for (int r0 = 0; r0 < JC; r0 += 8) {
        c4 qv[8];
        f4 xv[8];
#pragma unroll
        for (int j = 0; j < 8; ++j) {               // 8 loads in flight
            if (UC)
                qv[j] = *reinterpret_cast<const c4*>(codes + base + (size_t)(r0 + j) * Cdim);
            else
                xv[j] = *reinterpret_cast<const f4*>(x + base + (size_t)(r0 + j) * Cdim);
        }
#pragma unroll
        for (int j = 0; j < 8; ++j) {
            float xq0, xq1, xq2, xq3;
            if (UC) {
                xq0 = (float)qv[j][0] * s; xq1 = (float)qv[j][1] * s;
                xq2 = (float)qv[j][2] * s; xq3 = (float)qv[j][3] * s;
            } else {
                xq0 = code8f(xv[j][0], sinv) * s; xq1 = code8f(xv[j][1], sinv) * s;
                xq2 = code8f(xv[j][2], sinv) * s; xq3 = code8f(xv[j][3], sinv) * s;
            }
            acc[0] += eq_from(xq0, gm[0], ssub_inv, ssub);
            acc[1] += eq_from(xq1, gm[1], ssub_inv, ssub);
            acc[2] += eq_from(xq2, gm[2], ssub_inv, ssub);
            acc[3] += eq_from(xq3, gm[3], ssub_inv, ssub);
        }
    }
    *reinterpret_cast<f4*>(psum + (size_t)jc * NG + b * Cdim + c0) = acc;  // [jc][g]
}

// ---------------- K4: group sums + global max/min s (R3 reduce2 tree) ----------------
__global__ __launch_bounds__(256) void k_r2(char* __restrict__ ws) {
    const float* psum = (const float*)(ws + PSUM_B);
    float* sarr = (float*)(ws + SARR_B);
    float* sc   = (float*)(ws + SC_B);

    const int ci  = threadIdx.x & 31;
    const int sub = threadIdx.x >> 5;
    const int g   = blockIdx.x * 32 + ci;

    float p = 0.0f;
    for (int ch = sub; ch < NJC; ch += 8)          // ascending, step 8 (= R3 order)
        p += psum[(size_t)ch * NG + g];
    __shared__ float sp[8][32];
    sp[sub][ci] = p;
    __syncthreads();
    for (int off = 4; off; off >>= 1) {
        if (sub < off) sp[sub][ci] += sp[sub + off][ci];
        __syncthreads();
    }
    __shared__ float smx[32], smn[32];
    if (sub == 0) {
        const float tv = sp[0][ci];
        sarr[g] = tv;
        smx[ci] = tv; smn[ci] = tv;
    }
    __syncthreads();
    if (threadIdx.x == 0) {
        float mx = smx[0], mn = smn[0];
#pragma unroll
        for (int i = 1; i < 32; ++i) { mx = fmaxf(mx, smx[i]); mn = fminf(mn, smn[i]); }
        atomicMax(reinterpret_cast<unsigned int*>(sc + 1), __float_as_uint(mx));
        atomicMin(reinterpret_cast<unsigned int*>(sc + 2), __float_as_uint(mn));
    }
}

// ---------------- K5: output pass (validated R9 k_p3) ----------------
template <bool UC>
__global__ __launch_bounds__(256) void k_p3(const float* __restrict__ x,
                                            const float* __restrict__ scale,
                                            const char* __restrict__ ws,
                                            float* __restrict__ out) {
    const int b  = blockIdx.x / NJC;
    const int jc = blockIdx.x % NJC;
    const int c0 = threadIdx.x * 4;
    const float s = scale[0];
    const float sinv = 1.0f / s;
    const float* sc   = (const float*)(ws + SC_B);
    const float* gmv  = (const float*)(ws + GMV_B);
    const float* sarr = (const float*)(ws + SARR_B);
    const signed char* codes = (const signed char*)(ws + CODES_B);

    const float amax = fmaxf(sc[0], 1e-9f);
    const float ssub = amax / 32767.0f;
    const float ssub_inv = 1.0f / ssub;

    const float max_s = sc[1];
    const float min_s = sc[2];
    // fq monotone: min s_q = fq(min s); max r = 1/min s_q; max r_q = fq(max r)
    const float scale_s = fmaxf(max_s, 1e-9f) / 32767.0f;
    const float ss_inv  = 1.0f / scale_s;
    const float minsq   = fminf(fmaxf(rintf(min_s * ss_inv), -32768.0f), 32767.0f) * scale_s;
    const float maxr    = 1.0f / minsq;
    const float scale_r = fmaxf(maxr, 1e-9f) / 32767.0f;
    const float sr_inv  = 1.0f / scale_r;
    const float maxrq   = fminf(fmaxf(rintf(maxr * sr_inv), -32768.0f), 32767.0f) * scale_r;
    const float scale_out = fmaxf(maxrq, 1e-9f) / 127.0f;
    const float so_inv  = 1.0f / scale_out;

    const f4 gmc = *reinterpret_cast<const f4*>(gmv + b * Cdim + c0);
    const f4 gm  = {gmc[0] * s, gmc[1] * s, gmc[2] * s, gmc[3] * s};
    const f4 s4  = *reinterpret_cast<const f4*>(sarr + b * Cdim + c0);

    f4 rq;
#pragma unroll
    for (int i = 0; i < 4; ++i) {
        float qv = fminf(fmaxf(rintf(s4[i] * ss_inv), -32768.0f), 32767.0f) * scale_s;
        rq[i] = fminf(fmaxf(rintf((1.0f / qv) * sr_inv), -32768.0f), 32767.0f) * scale_r;
    }

    const size_t base = ((size_t)(b * Jdim + jc * JC)) * Cdim + c0;
#pragma unroll
    for (int r0 = 0; r0 < JC; r0 += 8) {
        c4 qv[8];
        f4 xv[8];
#pragma unroll
        for (int j = 0; j < 8; ++j) {               // 8 loads in flight
            if (UC)
                qv[j] = *reinterpret_cast<const c4*>(codes + base + (size_t)(r0 + j) * Cdim);
            else
                xv[j] = *reinterpret_cast<const f4*>(x + base + (size_t)(r0 + j) * Cdim);
        }
#pragma unroll
        for (int j = 0; j < 8; ++j) {
            float xq0, xq1, xq2, xq3;
            if (UC) {
                xq0 = (float)qv[j][0] * s; xq1 = (float)qv[j][1] * s;
                xq2 = (float)qv[j][2] * s; xq3 = (float)qv[j][3] * s;
            } else {
                xq0 = code8f(xv[j][0], sinv) * s; xq1 = code8f(xv[j][1], sinv) * s;
                xq2 = code8f(xv[j][2], sinv) * s; xq3 = code8f(xv[j][3], sinv) * s;
            }
            const float e0 = eq_from(xq0, gm[0], ssub_inv, ssub) * rq[0];
            const float e1 = eq_from(xq1, gm[1], ssub_inv, ssub) * rq[1];
            const float e2 = eq_from(xq2, gm[2], ssub_inv, ssub) * rq[2];
            const float e3 = eq_from(xq3, gm[3], ssub_inv, ssub) * rq[3];
            f4 o;
            o[0] = fminf(fmaxf(rintf(e0 * so_inv), -128.0f), 127.0f) * scale_out;
            o[1] = fminf(fmaxf(rintf(e1 * so_inv), -128.0f), 127.0f) * scale_out;
            o[2] = fminf(fmaxf(rintf(e2 * so_inv), -128.0f), 127.0f) * scale_out;
            o[3] = fminf(fmaxf(rintf(e3 * so_inv), -128.0f), 127.0f) * scale_out;
            __builtin_nontemporal_store(o,
                reinterpret_cast<f4*>(out + base + (size_t)(r0 + j) * Cdim));
        }
    }
}

extern "C" void kernel_launch(void* const* d_in, const int* in_sizes, int n_in,
                              void* d_out, int out_size, void* d_ws, size_t ws_size,
                              hipStream_t stream) {
    const float* x     = (const float*)d_in[0];
    const float* scale = (const float*)d_in[1];
    float* out = (float*)d_out;
    char* ws   = (char*)d_ws;

    if (ws_size >= WS_NEED) {
        k_p1<true ><<<GRID1, 256, 0, stream>>>(x, scale, ws);
        k_r1<<<NG / 32, 256, 0, stream>>>(scale, ws);
        k_p2<true ><<<GRID1, 256, 0, stream>>>(x, scale, ws);
        k_r2<<<NG / 32, 256, 0, stream>>>(ws);
        k_p3<true ><<<GRID1, 256, 0, stream>>>(x, scale, ws, out);
    } else {
        // no-codes fallback: K3/K5 recompute xq from x (bit-identical)
        k_p1<false><<<GRID1, 256, 0, stream>>>(x, scale, ws);
        k_r1<<<NG / 32, 256, 0, stream>>>(scale, ws);
        k_p2<false><<<GRID1, 256, 0, stream>>>(x, scale, ws);
        k_r2<<<NG / 32, 256, 0, stream>>>(ws);
        k_p3<false><<<GRID1, 256, 0, stream>>>(x, scale, ws, out);
    }
}

// Round 12
// 95.157 us; speedup vs baseline: 3.4101x; 1.0349x over previous
//
#include <hip/hip_runtime.h>
#include <math.h>

// Quantized softmax over axis 1 of x(8, 4096, 1024) fp32.
// Groups: (b, c) column, 8192 groups of 4096 elements (stride 1024 floats).
//
// Round-12 = Round-11 (98.5us, best) with three targeted cuts:
//   - P2 at JC2=64: psum 8MB->2MB, R2 reads 64 chunks not 256.
//   - R1 vectorized: c4 quad-group loads (64 blocks), coalesced; max/min
//     order-insensitive -> bit-identical.
//   - P1/P3/R2-tree/scale-derivations untouched (proven).
// Structure ledger: coop fusion dead (R10: grid sync ~50us each); col-slab
// dead (R9: +11us); row-chunk 5-kernel pipeline is the winning shape.
//   K1 p1: x (NT, 8-deep) -> codes(32MB) + [jc][g] max/min partials.
//   K2 r1: partials -> gmv[g] + global amax_sub (atomicMax).
//   K3 p2: codes (8-deep) -> psum[64][8192] (64-row partial sums).
//   K4 r2: psum -> sarr[g] + global max/min s (atomics).
//   K5 p3: codes + scalars -> out (NT stores, 8-deep).
// Atomics: uint max/min only (order-independent -> deterministic).

typedef float       f4 __attribute__((ext_vector_type(4)));
typedef signed char c4 __attribute__((ext_vector_type(4)));

static constexpr int Bdim = 8;
static constexpr int Jdim = 4096;
static constexpr int Cdim = 1024;
static constexpr int NG   = Bdim * Cdim;       // 8192 groups

static constexpr int JC    = 16;               // rows per P1/P3 chunk
static constexpr int NJC   = Jdim / JC;        // 256
static constexpr int GRID1 = Bdim * NJC;       // 2048
static constexpr int JC2   = 64;               // rows per P2 chunk
static constexpr int NJC2  = Jdim / JC2;       // 64
static constexpr int GRID2 = Bdim * NJC2;      // 512

// ---- ws byte offsets ----
static constexpr size_t SC_B    = 0;                               // f32[3]
static constexpr size_t GMV_B   = 4096;                            // f32[8192] gmax CODE
static constexpr size_t SARR_B  = GMV_B + (size_t)NG * 4;          // f32[8192]
static constexpr size_t PMAX_B  = 131072;                          // i8[256][8192]
static constexpr size_t PMIN_B  = PMAX_B + (size_t)NJC * NG;
static constexpr size_t PSUM_B  = PMIN_B + (size_t)NJC * NG;       // f32[64][8192] = 2MB
static constexpr size_t CODES_B = PSUM_B + (size_t)NJC * NG * 4;   // (region reserved as before)
static constexpr size_t WS_NEED = CODES_B + (size_t)Bdim * Jdim * Cdim;  // ~44MB

__device__ __forceinline__ float code8f(float x, float sinv) {
    // int8 code as float; rintf = round-half-even matches jnp.round
    return fminf(fmaxf(rintf(x * sinv), -128.0f), 127.0f);
}
// e_q = fq16(exp(fq16(clip(xq - gmax, -12, 0)))); scale_e = 1/32767 exactly
// (group-max element has sub==0 -> e==1 -> absmax(e)==1).
__device__ __forceinline__ float eq_from(float xq, float gmv, float ssub_inv, float ssub) {
    float sub = fminf(fmaxf(xq - gmv, -12.0f), 0.0f);
    float q   = rintf(sub * ssub_inv);
    float e   = __expf(q * ssub);
    return rintf(e * 32767.0f) * (1.0f / 32767.0f);
}
__device__ __forceinline__ f4 fmax4v(f4 a, f4 b) {
    f4 r; r[0]=fmaxf(a[0],b[0]); r[1]=fmaxf(a[1],b[1]);
    r[2]=fmaxf(a[2],b[2]); r[3]=fmaxf(a[3],b[3]); return r;
}
__device__ __forceinline__ f4 fmin4v(f4 a, f4 b) {
    f4 r; r[0]=fminf(a[0],b[0]); r[1]=fminf(a[1],b[1]);
    r[2]=fminf(a[2],b[2]); r[3]=fminf(a[3],b[3]); return r;
}

// ---------------- K1: quantize pass (unchanged from R11) ----------------
template <bool WC>
__global__ __launch_bounds__(256) void k_p1(const float* __restrict__ x,
                                            const float* __restrict__ scale,
                                            char* __restrict__ ws) {
    float* sc = (float*)(ws + SC_B);
    if (blockIdx.x == 0 && threadIdx.x == 0) {
        sc[0] = 0.0f;                        // amax_sub (atomicMax, >=0)
        sc[1] = 0.0f;                        // max_s    (atomicMax, >0)
        sc[2] = __int_as_float(0x7f800000);  // min_s = +inf (atomicMin)
    }
    const int b  = blockIdx.x / NJC;
    const int jc = blockIdx.x % NJC;
    const int c0 = threadIdx.x * 4;
    const float sinv = 1.0f / scale[0];
    const size_t base = ((size_t)(b * Jdim + jc * JC)) * Cdim + c0;
    signed char* codes = (signed char*)(ws + CODES_B);

    f4 vmax = {-1e30f, -1e30f, -1e30f, -1e30f};
    f4 vmin = { 1e30f,  1e30f,  1e30f,  1e30f};
#pragma unroll
    for (int r0 = 0; r0 < JC; r0 += 8) {
        f4 v[8];
#pragma unroll
        for (int j = 0; j < 8; ++j)                 // 8 loads in flight
            v[j] = __builtin_nontemporal_load(
                reinterpret_cast<const f4*>(x + base + (size_t)(r0 + j) * Cdim));
#pragma unroll
        for (int j = 0; j < 8; ++j) {
            f4 q;
            q[0] = code8f(v[j][0], sinv); q[1] = code8f(v[j][1], sinv);
            q[2] = code8f(v[j][2], sinv); q[3] = code8f(v[j][3], sinv);
            vmax = fmax4v(vmax, q); vmin = fmin4v(vmin, q);
            if (WC)
                *reinterpret_cast<c4*>(codes + base + (size_t)(r0 + j) * Cdim) =
                    (c4){(signed char)(int)q[0], (signed char)(int)q[1],
                         (signed char)(int)q[2], (signed char)(int)q[3]};
        }
    }
    const size_t pidx = (size_t)jc * NG + b * Cdim + c0;   // [jc][g] coalesced
    *reinterpret_cast<c4*>(ws + PMAX_B + pidx) =
        (c4){(signed char)(int)vmax[0], (signed char)(int)vmax[1],
             (signed char)(int)vmax[2], (signed char)(int)vmax[3]};
    *reinterpret_cast<c4*>(ws + PMIN_B + pidx) =
        (c4){(signed char)(int)vmin[0], (signed char)(int)vmin[1],
             (signed char)(int)vmin[2], (signed char)(int)vmin[3]};
}

// ---------------- K2: group gmax + global amax_sub (vectorized c4) ----------------
// 64 blocks x 256 thr; thread handles a quad of groups; max/min reductions are
// order-insensitive -> result bit-identical to R11's scalar version.
__global__ __launch_bounds__(256) void k_r1(const float* __restrict__ scale,
                                            char* __restrict__ ws) {
    const signed char* pmax8 = (const signed char*)(ws + PMAX_B);
    const signed char* pmin8 = (const signed char*)(ws + PMIN_B);
    float* gmv = (float*)(ws + GMV_B);
    float* sc  = (float*)(ws + SC_B);

    const int qi  = threadIdx.x & 31;             // quad index
    const int sub = threadIdx.x >> 5;             // 0..7
    const size_t g4 = (size_t)blockIdx.x * 128 + qi * 4;

    int mx0 = -128, mx1 = -128, mx2 = -128, mx3 = -128;
    int mn0 =  127, mn1 =  127, mn2 =  127, mn3 =  127;
    for (int jc = sub; jc < NJC; jc += 8) {
        const c4 a = *reinterpret_cast<const c4*>(pmax8 + (size_t)jc * NG + g4);
        const c4 b = *reinterpret_cast<const c4*>(pmin8 + (size_t)jc * NG + g4);
        mx0 = max(mx0, (int)a[0]); mx1 = max(mx1, (int)a[1]);
        mx2 = max(mx2, (int)a[2]); mx3 = max(mx3, (int)a[3]);
        mn0 = min(mn0, (int)b[0]); mn1 = min(mn1, (int)b[1]);
        mn2 = min(mn2, (int)b[2]); mn3 = min(mn3, (int)b[3]);
    }
    __shared__ int smx[8][32][4], smn[8][32][4];
    smx[sub][qi][0] = mx0; smx[sub][qi][1] = mx1;
    smx[sub][qi][2] = mx2; smx[sub][qi][3] = mx3;
    smn[sub][qi][0] = mn0; smn[sub][qi][1] = mn1;
    smn[sub][qi][2] = mn2; smn[sub][qi][3] = mn3;
    __syncthreads();
    for (int off = 4; off; off >>= 1) {
        if (sub < off) {
#pragma unroll
            for (int i = 0; i < 4; ++i) {
                smx[sub][qi][i] = max(smx[sub][qi][i], smx[sub + off][qi][i]);
                smn[sub][qi][i] = min(smn[sub][qi][i], smn[sub + off][qi][i]);
            }
        }
        __syncthreads();
    }
    __shared__ float sd[32];
    if (sub == 0) {
        const float s = scale[0];
        f4 gq;
        float d = -1e30f;
#pragma unroll
        for (int i = 0; i < 4; ++i) {
            const float gx = (float)smx[0][qi][i];
            gq[i] = gx;
            d = fmaxf(d, fminf(12.0f, gx * s - (float)smn[0][qi][i] * s));
        }
        *reinterpret_cast<f4*>(gmv + g4) = gq;    // CODE values; consumers *s
        sd[qi] = d;
    }
    __syncthreads();
    if (threadIdx.x == 0) {
        float m = sd[0];
#pragma unroll
        for (int i = 1; i < 32; ++i) m = fmaxf(m, sd[i]);
        atomicMax(reinterpret_cast<unsigned int*>(sc + 0), __float_as_uint(m));
    }
}

// ---------------- K3: partial e_q sums, JC2=64 rows/block ----------------
template <bool UC>
__global__ __launch_bounds__(256) void k_p2(const float* __restrict__ x,
                                            const float* __restrict__ scale,
                                            char* __restrict__ ws) {
    const int b  = blockIdx.x / NJC2;
    const int jq = blockIdx.x % NJC2;
    const int c0 = threadIdx.x * 4;
    const float s = scale[0];
    const float sinv = 1.0f / s;
    const float* sc  = (const float*)(ws + SC_B);
    const float* gmv = (const float*)(ws + GMV_B);
    float* psum = (float*)(ws + PSUM_B);
    const signed char* codes = (const signed char*)(ws + CODES_B);

    const float amax = fmaxf(sc[0], 1e-9f);
    const float ssub = amax / 32767.0f;
    const float ssub_inv = 1.0f / ssub;
    const f4 gmc = *reinterpret_cast<const f4*>(gmv + b * Cdim + c0);
    const f4 gm  = {gmc[0] * s, gmc[1] * s, gmc[2] * s, gmc[3] * s};
    const size_t base = ((size_t)(b * Jdim + jq * JC2)) * Cdim + c0;

    f4 acc = {0.f, 0.f, 0.f, 0.f};
#pragma unroll
    for (int r0 = 0; r0 < JC2; r0 += 8) {
        c4 qv[8];
        f4 xv[8];
#pragma unroll
        for (int j = 0; j < 8; ++j) {               // 8 loads in flight
            if (UC)
                qv[j] = *reinterpret_cast<const c4*>(codes + base + (size_t)(r0 + j) * Cdim);
            else
                xv[j] = *reinterpret_cast<const f4*>(x + base + (size_t)(r0 + j) * Cdim);
        }
#pragma unroll
        for (int j = 0; j < 8; ++j) {
            float xq0, xq1, xq2, xq3;
            if (UC) {
                xq0 = (float)qv[j][0] * s; xq1 = (float)qv[j][1] * s;
                xq2 = (float)qv[j][2] * s; xq3 = (float)qv[j][3] * s;
            } else {
                xq0 = code8f(xv[j][0], sinv) * s; xq1 = code8f(xv[j][1], sinv) * s;
                xq2 = code8f(xv[j][2], sinv) * s; xq3 = code8f(xv[j][3], sinv) * s;
            }
            acc[0] += eq_from(xq0, gm[0], ssub_inv, ssub);
            acc[1] += eq_from(xq1, gm[1], ssub_inv, ssub);
            acc[2] += eq_from(xq2, gm[2], ssub_inv, ssub);
            acc[3] += eq_from(xq3, gm[3], ssub_inv, ssub);
        }
    }
    *reinterpret_cast<f4*>(psum + (size_t)jq * NG + b * Cdim + c0) = acc;  // [jq][g]
}

// ---------------- K4: group sums + global max/min s (64 chunks) ----------------
__global__ __launch_bounds__(256) void k_r2(char* __restrict__ ws) {
    const float* psum = (const float*)(ws + PSUM_B);
    float* sarr = (float*)(ws + SARR_B);
    float* sc   = (float*)(ws + SC_B);

    const int ci  = threadIdx.x & 31;
    const int sub = threadIdx.x >> 5;
    const int g   = blockIdx.x * 32 + ci;

    float p = 0.0f;
    for (int ch = sub; ch < NJC2; ch += 8)         // ascending, step 8
        p += psum[(size_t)ch * NG + g];
    __shared__ float sp[8][32];
    sp[sub][ci] = p;
    __syncthreads();
    for (int off = 4; off; off >>= 1) {
        if (sub < off) sp[sub][ci] += sp[sub + off][ci];
        __syncthreads();
    }
    __shared__ float smx[32], smn[32];
    if (sub == 0) {
        const float tv = sp[0][ci];
        sarr[g] = tv;
        smx[ci] = tv; smn[ci] = tv;
    }
    __syncthreads();
    if (threadIdx.x == 0) {
        float mx = smx[0], mn = smn[0];
#pragma unroll
        for (int i = 1; i < 32; ++i) { mx = fmaxf(mx, smx[i]); mn = fminf(mn, smn[i]); }
        atomicMax(reinterpret_cast<unsigned int*>(sc + 1), __float_as_uint(mx));
        atomicMin(reinterpret_cast<unsigned int*>(sc + 2), __float_as_uint(mn));
    }
}

// ---------------- K5: output pass (unchanged from R11) ----------------
template <bool UC>
__global__ __launch_bounds__(256) void k_p3(const float* __restrict__ x,
                                            const float* __restrict__ scale,
                                            const char* __restrict__ ws,
                                            float* __restrict__ out) {
    const int b  = blockIdx.x / NJC;
    const int jc = blockIdx.x % NJC;
    const int c0 = threadIdx.x * 4;
    const float s = scale[0];
    const float sinv = 1.0f / s;
    const float* sc   = (const float*)(ws + SC_B);
    const float* gmv  = (const float*)(ws + GMV_B);
    const float* sarr = (const float*)(ws + SARR_B);
    const signed char* codes = (const signed char*)(ws + CODES_B);

    const float amax = fmaxf(sc[0], 1e-9f);
    const float ssub = amax / 32767.0f;
    const float ssub_inv = 1.0f / ssub;

    const float max_s = sc[1];
    const float min_s = sc[2];
    // fq monotone: min s_q = fq(min s); max r = 1/min s_q; max r_q = fq(max r)
    const float scale_s = fmaxf(max_s, 1e-9f) / 32767.0f;
    const float ss_inv  = 1.0f / scale_s;
    const float minsq   = fminf(fmaxf(rintf(min_s * ss_inv), -32768.0f), 32767.0f) * scale_s;
    const float maxr    = 1.0f / minsq;
    const float scale_r = fmaxf(maxr, 1e-9f) / 32767.0f;
    const float sr_inv  = 1.0f / scale_r;
    const float maxrq   = fminf(fmaxf(rintf(maxr * sr_inv), -32768.0f), 32767.0f) * scale_r;
    const float scale_out = fmaxf(maxrq, 1e-9f) / 127.0f;
    const float so_inv  = 1.0f / scale_out;

    const f4 gmc = *reinterpret_cast<const f4*>(gmv + b * Cdim + c0);
    const f4 gm  = {gmc[0] * s, gmc[1] * s, gmc[2] * s, gmc[3] * s};
    const f4 s4  = *reinterpret_cast<const f4*>(sarr + b * Cdim + c0);

    f4 rq;
#pragma unroll
    for (int i = 0; i < 4; ++i) {
        float qv = fminf(fmaxf(rintf(s4[i] * ss_inv), -32768.0f), 32767.0f) * scale_s;
        rq[i] = fminf(fmaxf(rintf((1.0f / qv) * sr_inv), -32768.0f), 32767.0f) * scale_r;
    }

    const size_t base = ((size_t)(b * Jdim + jc * JC)) * Cdim + c0;
#pragma unroll
    for (int r0 = 0; r0 < JC; r0 += 8) {
        c4 qv[8];
        f4 xv[8];
#pragma unroll
        for (int j = 0; j < 8; ++j) {               // 8 loads in flight
            if (UC)
                qv[j] = *reinterpret_cast<const c4*>(codes + base + (size_t)(r0 + j) * Cdim);
            else
                xv[j] = *reinterpret_cast<const f4*>(x + base + (size_t)(r0 + j) * Cdim);
        }
#pragma unroll
        for (int j = 0; j < 8; ++j) {
            float xq0, xq1, xq2, xq3;
            if (UC) {
                xq0 = (float)qv[j][0] * s; xq1 = (float)qv[j][1] * s;
                xq2 = (float)qv[j][2] * s; xq3 = (float)qv[j][3] * s;
            } else {
                xq0 = code8f(xv[j][0], sinv) * s; xq1 = code8f(xv[j][1], sinv) * s;
                xq2 = code8f(xv[j][2], sinv) * s; xq3 = code8f(xv[j][3], sinv) * s;
            }
            const float e0 = eq_from(xq0, gm[0], ssub_inv, ssub) * rq[0];
            const float e1 = eq_from(xq1, gm[1], ssub_inv, ssub) * rq[1];
            const float e2 = eq_from(xq2, gm[2], ssub_inv, ssub) * rq[2];
            const float e3 = eq_from(xq3, gm[3], ssub_inv, ssub) * rq[3];
            f4 o;
            o[0] = fminf(fmaxf(rintf(e0 * so_inv), -128.0f), 127.0f) * scale_out;
            o[1] = fminf(fmaxf(rintf(e1 * so_inv), -128.0f), 127.0f) * scale_out;
            o[2] = fminf(fmaxf(rintf(e2 * so_inv), -128.0f), 127.0f) * scale_out;
            o[3] = fminf(fmaxf(rintf(e3 * so_inv), -128.0f), 127.0f) * scale_out;
            __builtin_nontemporal_store(o,
                reinterpret_cast<f4*>(out + base + (size_t)(r0 + j) * Cdim));
        }
    }
}

extern "C" void kernel_launch(void* const* d_in, const int* in_sizes, int n_in,
                              void* d_out, int out_size, void* d_ws, size_t ws_size,
                              hipStream_t stream) {
    const float* x     = (const float*)d_in[0];
    const float* scale = (const float*)d_in[1];
    float* out = (float*)d_out;
    char* ws   = (char*)d_ws;

    if (ws_size >= WS_NEED) {
        k_p1<true ><<<GRID1, 256, 0, stream>>>(x, scale, ws);
        k_r1<<<NG / 128, 256, 0, stream>>>(scale, ws);
        k_p2<true ><<<GRID2, 256, 0, stream>>>(x, scale, ws);
        k_r2<<<NG / 32, 256, 0, stream>>>(ws);
        k_p3<true ><<<GRID1, 256, 0, stream>>>(x, scale, ws, out);
    } else {
        // no-codes fallback: K3/K5 recompute xq from x (bit-identical)
        k_p1<false><<<GRID1, 256, 0, stream>>>(x, scale, ws);
        k_r1<<<NG / 128, 256, 0, stream>>>(scale, ws);
        k_p2<false><<<GRID2, 256, 0, stream>>>(x, scale, ws);
        k_r2<<<NG / 32, 256, 0, stream>>>(ws);
        k_p3<false><<<GRID1, 256, 0, stream>>>(x, scale, ws, out);
    }
}